// Round 1
// baseline (1198.226 us; speedup 1.0000x reference)
//
#include <hip/hip_runtime.h>

// Switch-MoE: top-1 routing + 3 grouped GEMMs (bf16 MFMA), exact GELU.
// T=8192 tokens, D=1024, E=8 experts, hidden 4096 -> 2048 -> 1024.

#define T_TOK 8192
#define D_DIM 1024
#define E_NUM 8

typedef __attribute__((ext_vector_type(4))) float f32x4;
typedef __attribute__((ext_vector_type(8))) short bf16x8;

__device__ __forceinline__ unsigned short f2bf(float f) {
  unsigned u = __float_as_uint(f);
  u += 0x7fffu + ((u >> 16) & 1u);   // RNE
  return (unsigned short)(u >> 16);
}

__device__ __forceinline__ void gl_lds16(const void* g, void* l) {
  __builtin_amdgcn_global_load_lds(
      (const __attribute__((address_space(1))) unsigned int*)g,
      (__attribute__((address_space(3))) unsigned int*)l, 16, 0, 0);
}

// meta layout (ints): [0]=n_tiles [1..9]=off[0..8] [10..17]=counts
// [20..27]=cursors [32..103]=tile_list (e<<16|mt)
__global__ void k_init(int* meta) { meta[threadIdx.x] = 0; }

__global__ __launch_bounds__(256) void k_router(
    const float* __restrict__ x, const float* __restrict__ Wr,
    const float* __restrict__ br, int* __restrict__ eid, int* __restrict__ meta) {
  int tk = blockIdx.x * 4 + (threadIdx.x >> 6);
  int l = threadIdx.x & 63;
  const float* xr = x + (size_t)tk * D_DIM;
  double acc[8];
#pragma unroll
  for (int e = 0; e < 8; ++e) acc[e] = 0.0;
  for (int it = 0; it < D_DIM / 64; ++it) {
    int d = it * 64 + l;
    double xd = (double)xr[d];
    const float4* wp = (const float4*)(Wr + (size_t)d * 8);
    float4 w0 = wp[0], w1 = wp[1];
    acc[0] += xd * (double)w0.x; acc[1] += xd * (double)w0.y;
    acc[2] += xd * (double)w0.z; acc[3] += xd * (double)w0.w;
    acc[4] += xd * (double)w1.x; acc[5] += xd * (double)w1.y;
    acc[6] += xd * (double)w1.z; acc[7] += xd * (double)w1.w;
  }
#pragma unroll
  for (int e = 0; e < 8; ++e)
    for (int off = 32; off > 0; off >>= 1)
      acc[e] += __shfl_down(acc[e], off);
  if (l == 0) {
    int best = 0; double bv = acc[0] + (double)br[0];
#pragma unroll
    for (int e = 1; e < 8; ++e) {
      double v = acc[e] + (double)br[e];
      if (v > bv) { bv = v; best = e; }      // strict > : first-max tie-break (matches argmax)
    }
    eid[tk] = best;
    atomicAdd(&meta[10 + best], 1);
  }
}

__global__ void k_prefix(int* meta) {
  if (threadIdx.x != 0) return;
  int off = 0, nt = 0;
  for (int e = 0; e < 8; ++e) {
    int c = meta[10 + e];
    meta[1 + e] = off;
    meta[20 + e] = off;
    int ntile = (c + 127) >> 7;
    for (int m = 0; m < ntile; ++m) meta[32 + nt++] = (e << 16) | m;
    off += c;
  }
  meta[9] = off;
  meta[0] = nt;
}

__global__ __launch_bounds__(256) void k_scatter(
    const float* __restrict__ x, const int* __restrict__ eid,
    int* __restrict__ meta, int* __restrict__ tokmap, unsigned short* __restrict__ Xs) {
  int tk = blockIdx.x;
  __shared__ int srow;
  if (threadIdx.x == 0) {
    int e = eid[tk];
    int i = atomicAdd(&meta[20 + e], 1);
    tokmap[i] = tk;
    srow = i;
  }
  __syncthreads();
  int i = srow;
  float4 v = ((const float4*)(x + (size_t)tk * D_DIM))[threadIdx.x];
  unsigned long long p = (unsigned long long)f2bf(v.x)
                       | ((unsigned long long)f2bf(v.y) << 16)
                       | ((unsigned long long)f2bf(v.z) << 32)
                       | ((unsigned long long)f2bf(v.w) << 48);
  *(unsigned long long*)(Xs + (size_t)i * D_DIM + threadIdx.x * 4) = p;
}

// fp32 [E][K][N] -> bf16 [E][N][K]
__global__ __launch_bounds__(256) void k_transpose(
    const float* __restrict__ W, unsigned short* __restrict__ Wt, int K, int N) {
  int e = blockIdx.z;
  W += (size_t)e * K * N;
  Wt += (size_t)e * K * N;
  int k0 = blockIdx.x * 32, n0 = blockIdx.y * 32;
  __shared__ float tile[32][33];
  int r = threadIdx.x >> 3, c4 = (threadIdx.x & 7) * 4;
  float4 v = *(const float4*)(W + (size_t)(k0 + r) * N + n0 + c4);
  tile[r][c4] = v.x; tile[r][c4 + 1] = v.y; tile[r][c4 + 2] = v.z; tile[r][c4 + 3] = v.w;
  __syncthreads();
  unsigned long long p = (unsigned long long)f2bf(tile[c4][r])
                       | ((unsigned long long)f2bf(tile[c4 + 1][r]) << 16)
                       | ((unsigned long long)f2bf(tile[c4 + 2][r]) << 32)
                       | ((unsigned long long)f2bf(tile[c4 + 3][r]) << 48);
  *(unsigned long long*)(Wt + (size_t)(n0 + r) * K + k0 + c4) = p;
}

// Grouped GEMM: C[rows, N] = A[rows, K] @ Wt[e]^T (+bias, opt GELU).
// 128x128 tile, BK=64, 4 waves (2x2), 16x16x32 bf16 MFMA.
// LDS tiles XOR-swizzled: LDS[r][cb] = G[r][cb ^ ((r&7)<<4)] via pre-swizzled source.
template <bool GELU, bool SCATTER>
__global__ __launch_bounds__(256) void moe_gemm(
    const unsigned short* __restrict__ A, const unsigned short* __restrict__ Wt,
    const float* __restrict__ bias, const int* __restrict__ meta,
    const int* __restrict__ tokmap, unsigned short* __restrict__ Obf,
    float* __restrict__ Of, int K, int N) {
  if ((int)blockIdx.x >= meta[0]) return;
  int tl = meta[32 + blockIdx.x];
  int e = tl >> 16, mt = tl & 0xffff;
  int row0 = meta[1 + e] + mt * 128;
  int rowend = meta[2 + e];
  int ncol0 = blockIdx.y * 128;

  __shared__ char As[128 * 64 * 2];
  __shared__ char Bs[128 * 64 * 2];

  int t = threadIdx.x;
  int w = t >> 6, l = t & 63;
  int wm = w >> 1, wn = w & 1;
  size_t Kb = (size_t)K * 2;
  const char* Ab = (const char*)A;
  const char* Bb = (const char*)(Wt + (size_t)e * N * K);
  int sr = t >> 3;            // staging row 0..31
  int scb = (t & 7) << 4;     // staging byte-col 0..112

  f32x4 acc[4][4];
#pragma unroll
  for (int m = 0; m < 4; ++m)
#pragma unroll
    for (int n = 0; n < 4; ++n) acc[m][n] = (f32x4)(0.0f);

  for (int kt = 0; kt < K; kt += 64) {
#pragma unroll
    for (int i = 0; i < 4; ++i) {
      int r = i * 32 + sr;
      int gr = row0 + r;
      if (gr > rowend - 1) gr = rowend - 1;   // clamp padding rows
      gl_lds16(Ab + (size_t)gr * Kb + (size_t)(kt << 1) + (scb ^ ((r & 7) << 4)),
               As + (i * 32 + w * 8) * 128);
    }
#pragma unroll
    for (int i = 0; i < 4; ++i) {
      int r = i * 32 + sr;
      gl_lds16(Bb + (size_t)(ncol0 + r) * Kb + (size_t)(kt << 1) + (scb ^ ((r & 7) << 4)),
               Bs + (i * 32 + w * 8) * 128);
    }
    __syncthreads();
#pragma unroll
    for (int kh = 0; kh < 2; ++kh) {
      bf16x8 af[4], bfr[4];
      int cb = ((l >> 4) << 4) + (kh << 6);
#pragma unroll
      for (int m = 0; m < 4; ++m) {
        int row = wm * 64 + m * 16 + (l & 15);
        af[m] = *(const bf16x8*)(As + row * 128 + (cb ^ ((row & 7) << 4)));
      }
#pragma unroll
      for (int n = 0; n < 4; ++n) {
        int col = wn * 64 + n * 16 + (l & 15);
        bfr[n] = *(const bf16x8*)(Bs + col * 128 + (cb ^ ((col & 7) << 4)));
      }
#pragma unroll
      for (int m = 0; m < 4; ++m)
#pragma unroll
        for (int n = 0; n < 4; ++n)
          acc[m][n] = __builtin_amdgcn_mfma_f32_16x16x32_bf16(af[m], bfr[n], acc[m][n], 0, 0, 0);
    }
    __syncthreads();
  }

  // epilogue: C/D layout col=lane&15, row=(lane>>4)*4+r
  int lr = (l >> 4) << 2, lc = l & 15;
#pragma unroll
  for (int n = 0; n < 4; ++n) {
    int col = ncol0 + wn * 64 + n * 16 + lc;
    float bv = bias[(size_t)e * N + col];
#pragma unroll
    for (int m = 0; m < 4; ++m) {
      int rb = row0 + wm * 64 + m * 16 + lr;
#pragma unroll
      for (int r = 0; r < 4; ++r) {
        int grow = rb + r;
        if (grow >= rowend) continue;
        float v = acc[m][n][r] + bv;
        if (GELU) v = 0.5f * v * (1.0f + erff(v * 0.70710678118654752f));
        if (SCATTER) Of[(size_t)tokmap[grow] * N + col] = v;
        else Obf[(size_t)grow * N + col] = f2bf(v);
      }
    }
  }
}

extern "C" void kernel_launch(void* const* d_in, const int* in_sizes, int n_in,
                              void* d_out, int out_size, void* d_ws, size_t ws_size,
                              hipStream_t stream) {
  const float* x  = (const float*)d_in[0];
  const float* Wr = (const float*)d_in[1];
  const float* br = (const float*)d_in[2];
  const float* W1 = (const float*)d_in[3];
  const float* b1 = (const float*)d_in[4];
  const float* W2 = (const float*)d_in[5];
  const float* b2 = (const float*)d_in[6];
  const float* W3 = (const float*)d_in[7];
  const float* b3 = (const float*)d_in[8];
  float* out = (float*)d_out;

  char* ws = (char*)d_ws;
  const size_t MB = 1ull << 20;
  int* meta = (int*)ws;
  int* eid = (int*)(ws + 4096);
  int* tokmap = (int*)(ws + 36864);
  unsigned short* Xs  = (unsigned short*)(ws + 1 * MB);    // 16 MB
  unsigned short* H1  = (unsigned short*)(ws + 17 * MB);   // 64 MB
  unsigned short* H2  = (unsigned short*)(ws + 81 * MB);   // 32 MB
  unsigned short* W1t = (unsigned short*)(ws + 113 * MB);  // 64 MB
  unsigned short* W2t = (unsigned short*)(ws + 177 * MB);  // 128 MB
  unsigned short* W3t = (unsigned short*)(ws + 305 * MB);  // 32 MB

  k_init<<<1, 256, 0, stream>>>(meta);
  k_router<<<T_TOK / 4, 256, 0, stream>>>(x, Wr, br, eid, meta);
  k_prefix<<<1, 64, 0, stream>>>(meta);
  k_scatter<<<T_TOK, 256, 0, stream>>>(x, eid, meta, tokmap, Xs);
  k_transpose<<<dim3(D_DIM / 32, 4096 / 32, E_NUM), 256, 0, stream>>>(W1, W1t, D_DIM, 4096);
  k_transpose<<<dim3(4096 / 32, 2048 / 32, E_NUM), 256, 0, stream>>>(W2, W2t, 4096, 2048);
  k_transpose<<<dim3(2048 / 32, 1024 / 32, E_NUM), 256, 0, stream>>>(W3, W3t, 2048, 1024);
  moe_gemm<true, false><<<dim3(72, 4096 / 128), 256, 0, stream>>>(
      Xs, W1t, b1, meta, tokmap, H1, nullptr, D_DIM, 4096);
  moe_gemm<true, false><<<dim3(72, 2048 / 128), 256, 0, stream>>>(
      H1, W2t, b2, meta, tokmap, H2, nullptr, 4096, 2048);
  moe_gemm<false, true><<<dim3(72, 1024 / 128), 256, 0, stream>>>(
      H2, W3t, b3, meta, tokmap, nullptr, out, 2048, 1024);
}